// Round 3
// baseline (2001.125 us; speedup 1.0000x reference)
//
#include <hip/hip_runtime.h>
#include <math.h>

#define H 16
#define HD 64
#define DDIM 1024
#define LSEQ 1024
#define BATCH 4
#define TOPK 102
#define INV_SCALE 0.125f
#define MROWS (LSEQ * BATCH)   // 4096
#define QKVN (3 * DDIM)        // 3072
#define HBL (H * BATCH * LSEQ) // 65536

// ---------------- fp32 tiled GEMM: C = A(M,K) * B(N,K)^T + bias(N) ----------------
// 128x128 tile, 8x8 split microtile. PERMUTE=true scatters output into
// Q/K/V buffers laid out (H,B,L,64) for the fused attention kernel.
#define BM 128
#define BN 128
#define BKK 16

template <bool PERMUTE>
__global__ __launch_bounds__(256)
void gemm_abT_bias(const float* __restrict__ A, const float* __restrict__ Bw,
                   const float* __restrict__ bias, float* __restrict__ C,
                   int Nd, int Kd) {
    __shared__ float As[BKK][BM + 4];
    __shared__ float Bs[BKK][BN + 4];
    const int tid = threadIdx.x;
    const int tx = tid & 15, ty = tid >> 4;
    const int bn = blockIdx.x * BN, bm = blockIdx.y * BM;
    const int lr = tid >> 1;          // 0..127
    const int lc = (tid & 1) * 8;     // 0 or 8
    const float* Aptr = A + (size_t)(bm + lr) * Kd + lc;
    const float* Bptr = Bw + (size_t)(bn + lr) * Kd + lc;

    float acc[2][2][4][4];
    #pragma unroll
    for (int r = 0; r < 2; ++r)
        #pragma unroll
        for (int c = 0; c < 2; ++c)
            #pragma unroll
            for (int i = 0; i < 4; ++i)
                #pragma unroll
                for (int j = 0; j < 4; ++j) acc[r][c][i][j] = 0.0f;

    float4 av0 = *(const float4*)(Aptr);
    float4 av1 = *(const float4*)(Aptr + 4);
    float4 bv0 = *(const float4*)(Bptr);
    float4 bv1 = *(const float4*)(Bptr + 4);

    for (int k0 = 0; k0 < Kd; k0 += BKK) {
        __syncthreads();
        As[lc + 0][lr] = av0.x; As[lc + 1][lr] = av0.y; As[lc + 2][lr] = av0.z; As[lc + 3][lr] = av0.w;
        As[lc + 4][lr] = av1.x; As[lc + 5][lr] = av1.y; As[lc + 6][lr] = av1.z; As[lc + 7][lr] = av1.w;
        Bs[lc + 0][lr] = bv0.x; Bs[lc + 1][lr] = bv0.y; Bs[lc + 2][lr] = bv0.z; Bs[lc + 3][lr] = bv0.w;
        Bs[lc + 4][lr] = bv1.x; Bs[lc + 5][lr] = bv1.y; Bs[lc + 6][lr] = bv1.z; Bs[lc + 7][lr] = bv1.w;
        __syncthreads();
        if (k0 + BKK < Kd) {
            av0 = *(const float4*)(Aptr + k0 + BKK);
            av1 = *(const float4*)(Aptr + k0 + BKK + 4);
            bv0 = *(const float4*)(Bptr + k0 + BKK);
            bv1 = *(const float4*)(Bptr + k0 + BKK + 4);
        }
        #pragma unroll
        for (int kk = 0; kk < BKK; ++kk) {
            float ar[8], br[8];
            *(float4*)&ar[0] = *(const float4*)&As[kk][ty * 4];
            *(float4*)&ar[4] = *(const float4*)&As[kk][64 + ty * 4];
            *(float4*)&br[0] = *(const float4*)&Bs[kk][tx * 4];
            *(float4*)&br[4] = *(const float4*)&Bs[kk][64 + tx * 4];
            #pragma unroll
            for (int r = 0; r < 2; ++r)
                #pragma unroll
                for (int i = 0; i < 4; ++i)
                    #pragma unroll
                    for (int c = 0; c < 2; ++c)
                        #pragma unroll
                        for (int j = 0; j < 4; ++j)
                            acc[r][c][i][j] += ar[r * 4 + i] * br[c * 4 + j];
        }
    }
    float4 bb[2];
    bb[0] = *(const float4*)&bias[bn + tx * 4];
    bb[1] = *(const float4*)&bias[bn + 64 + tx * 4];
    #pragma unroll
    for (int r = 0; r < 2; ++r)
        #pragma unroll
        for (int i = 0; i < 4; ++i) {
            const int row = bm + r * 64 + ty * 4 + i;
            #pragma unroll
            for (int c = 0; c < 2; ++c) {
                float4 o;
                o.x = acc[r][c][i][0] + bb[c].x;
                o.y = acc[r][c][i][1] + bb[c].y;
                o.z = acc[r][c][i][2] + bb[c].z;
                o.w = acc[r][c][i][3] + bb[c].w;
                if (!PERMUTE) {
                    *(float4*)&C[(size_t)row * Nd + bn + c * 64 + tx * 4] = o;
                } else {
                    const int col = bn + c * 64 + tx * 4;
                    const int which = col >> 10;          // 0=q,1=k,2=v
                    const int hh = (col >> 6) & 15;
                    const int d = col & 63;               // = tx*4
                    const int l = row >> 2, b2 = row & 3; // row = l*B + b
                    float* dst = C + (size_t)which * ((size_t)HBL * HD)
                               + (((size_t)(hh * BATCH + b2) * LSEQ + l) * HD + d);
                    *(float4*)dst = o;
                }
            }
        }
}

// ---------------- fused scores + topk + softmax + sparse PV ----------------
// One block per (h, b, 8 consecutive l rows). No global scores tensor.
__global__ __launch_bounds__(256)
void fused_attn(const float* __restrict__ Q, const float* __restrict__ K,
                const float* __restrict__ V, const float* __restrict__ S,
                float* __restrict__ attn) {
    __shared__ float qs[8][HD];          // 2 KB
    __shared__ float sc[8][LSEQ];        // 32 KB
    __shared__ int   idxs[8][TOPK];      // 3.2 KB
    __shared__ float wts[8][TOPK];       // 3.2 KB

    const int h = blockIdx.z, b = blockIdx.y, l0 = blockIdx.x * 8;
    const int tid = threadIdx.x;
    const size_t hb = (size_t)(h * BATCH + b) * LSEQ;

    // Phase A: stage the 8 q rows
    if (tid < 128) {
        const int r = tid >> 4, d4 = (tid & 15) * 4;
        *(float4*)&qs[r][d4] = *(const float4*)&Q[(hb + l0 + r) * HD + d4];
    }
    __syncthreads();

    // Phase B: scores for t = tid*4 .. tid*4+3 against all 8 rows
    const int t0 = tid * 4;
    float acc[8][4];
    #pragma unroll
    for (int r = 0; r < 8; ++r)
        #pragma unroll
        for (int c = 0; c < 4; ++c) acc[r][c] = 0.0f;

    const float* kp = K + (hb + t0) * HD;   // 4 K rows, 256B each, imm-offset reachable
    #pragma unroll
    for (int dc = 0; dc < 16; ++dc) {
        float4 k0 = *(const float4*)(kp + 0 * HD + dc * 4);
        float4 k1 = *(const float4*)(kp + 1 * HD + dc * 4);
        float4 k2 = *(const float4*)(kp + 2 * HD + dc * 4);
        float4 k3 = *(const float4*)(kp + 3 * HD + dc * 4);
        #pragma unroll
        for (int r = 0; r < 8; ++r) {
            float4 q4 = *(const float4*)&qs[r][dc * 4];
            acc[r][0] += q4.x * k0.x + q4.y * k0.y + q4.z * k0.z + q4.w * k0.w;
            acc[r][1] += q4.x * k1.x + q4.y * k1.y + q4.z * k1.z + q4.w * k1.w;
            acc[r][2] += q4.x * k2.x + q4.y * k2.y + q4.z * k2.z + q4.w * k2.w;
            acc[r][3] += q4.x * k3.x + q4.y * k3.y + q4.z * k3.z + q4.w * k3.w;
        }
    }
    #pragma unroll
    for (int r = 0; r < 8; ++r) {
        float4 s4 = *(const float4*)&S[((size_t)h * DDIM + (l0 + r)) * DDIM + t0];
        float4 o;
        o.x = acc[r][0] * INV_SCALE + __logf(s4.x + 1e-8f);
        o.y = acc[r][1] * INV_SCALE + __logf(s4.y + 1e-8f);
        o.z = acc[r][2] * INV_SCALE + __logf(s4.z + 1e-8f);
        o.w = acc[r][3] * INV_SCALE + __logf(s4.w + 1e-8f);
        *(float4*)&sc[r][t0] = o;
    }
    __syncthreads();

    // Phase C/D: per-wave (barrier-free) topk + softmax + sparse PV.
    // Wave w handles rows w and w+4. Lane owns t = i*64 + lane, i=0..15;
    // (i, lane) lexicographic order == ascending t, which keeps the
    // jax.lax.top_k tie rule (lowest index first) exact via ballots.
    const int wid = tid >> 6, lane = tid & 63;
    const unsigned long long lt = (1ull << lane) - 1ull;

    for (int rr = 0; rr < 2; ++rr) {
        const int r = wid + rr * 4;
        float s[16]; unsigned u[16];
        float mx = -INFINITY;
        #pragma unroll
        for (int i = 0; i < 16; ++i) {
            s[i] = sc[r][i * 64 + lane];
            const unsigned bits = __float_as_uint(s[i]);
            u[i] = ((int)bits < 0) ? ~bits : (bits | 0x80000000u);
            mx = fmaxf(mx, s[i]);
        }
        #pragma unroll
        for (int off = 32; off; off >>= 1) mx = fmaxf(mx, __shfl_xor(mx, off));

        // 32-step binary radix select for the TOPK-th largest key
        unsigned prefix = 0; int need = TOPK;
        for (int bit = 31; bit >= 0; --bit) {
            const unsigned candhi = (prefix >> bit) | 1u;
            int cnt = 0;
            #pragma unroll
            for (int i = 0; i < 16; ++i) cnt += (int)((u[i] >> bit) == candhi);
            #pragma unroll
            for (int off = 32; off; off >>= 1) cnt += __shfl_xor(cnt, off);
            if (cnt >= need) prefix |= (1u << bit);
            else need -= cnt;
        }

        // selection with exact tie rank (ascending t among ==threshold)
        float p[16]; unsigned selmask = 0; float lsum = 0.0f;
        int cum = 0;
        #pragma unroll
        for (int i = 0; i < 16; ++i) {
            const bool eq = (u[i] == prefix);
            const unsigned long long em = __ballot(eq);
            const int erank = cum + (int)__popcll(em & lt);
            cum += (int)__popcll(em);
            const bool sel = (u[i] > prefix) || (eq && erank < need);
            p[i] = sel ? __expf(s[i] - mx) : 0.0f;
            if (sel) selmask |= (1u << i);
            lsum += p[i];
        }
        #pragma unroll
        for (int off = 32; off; off >>= 1) lsum += __shfl_xor(lsum, off);
        const float inv = 1.0f / lsum;

        // compact (idx, weight) list in ascending-t order
        int pos = 0;
        #pragma unroll
        for (int i = 0; i < 16; ++i) {
            const bool sel = (selmask >> i) & 1u;
            const unsigned long long sm = __ballot(sel);
            const int mypos = pos + (int)__popcll(sm & lt);
            if (sel) { idxs[r][mypos] = i * 64 + lane; wts[r][mypos] = p[i] * inv; }
            pos += (int)__popcll(sm);
        }

        // sparse PV: lane = d
        const float* vb = V + hb * HD + lane;
        float o0 = 0.0f, o1 = 0.0f;
        for (int j = 0; j < TOPK; j += 2) {
            const int ta = idxs[r][j], tb = idxs[r][j + 1];
            const float wa = wts[r][j], wb = wts[r][j + 1];
            o0 += wa * vb[(size_t)ta * HD];
            o1 += wb * vb[(size_t)tb * HD];
        }
        attn[((size_t)(l0 + r) * BATCH + b) * DDIM + h * HD + lane] = o0 + o1;
    }
}

// ---------------- launcher ----------------
extern "C" void kernel_launch(void* const* d_in, const int* in_sizes, int n_in,
                              void* d_out, int out_size, void* d_ws, size_t ws_size,
                              hipStream_t stream) {
    (void)in_sizes; (void)n_in; (void)out_size; (void)ws_size;
    const float* x      = (const float*)d_in[0];
    const float* qkv_w  = (const float*)d_in[1];
    const float* qkv_b  = (const float*)d_in[2];
    const float* out_w  = (const float*)d_in[3];
    const float* out_b  = (const float*)d_in[4];
    const float* S      = (const float*)d_in[5];
    float* out = (float*)d_out;

    // workspace: Q|K|V (each HBL x 64) + attn (L*B x D)  = 67 MB total
    float* Q    = (float*)d_ws;
    float* Kb   = Q + (size_t)HBL * HD;
    float* V    = Kb + (size_t)HBL * HD;
    float* attn = V + (size_t)HBL * HD;

    // K1: qkv = x @ qkv_w^T + qkv_b, scattered into Q/K/V (H,B,L,64)
    gemm_abT_bias<true><<<dim3(QKVN / BN, MROWS / BM), 256, 0, stream>>>(
        x, qkv_w, qkv_b, Q, QKVN, DDIM);

    // K2: fused scores + topk + softmax + sparse PV
    fused_attn<<<dim3(LSEQ / 8, BATCH, H), 256, 0, stream>>>(Q, Kb, V, S, attn);

    // K3: out = attn @ out_w^T + out_b
    gemm_abT_bias<false><<<dim3(DDIM / BN, MROWS / BM), 256, 0, stream>>>(
        attn, out_w, out_b, out, DDIM, DDIM);
}